// Round 7
// baseline (976.072 us; speedup 1.0000x reference)
//
#include <hip/hip_runtime.h>

// ---------------------------------------------------------------------------
// GCN forward, bf16 activations / fp32 weights+accum.
// CSR: bucketed radix (dst>>9) with per-(node, src-bucket-of-8) sub-lists.
// Aggregate: phase-locked 8-pass gather — all blocks co-resident, each pass
// touches one 3.2MB (or 1.6MB) src slice so gathers hit per-XCD L2.
// Head: pool(h2) first (linearity), then tiny 64-graph GEMMs.
// ---------------------------------------------------------------------------

__device__ __forceinline__ unsigned short f2bf(float f) {
    unsigned int u = __builtin_bit_cast(unsigned int, f);
    u = (u + 0x7FFFu + ((u >> 16) & 1u)) >> 16;
    return (unsigned short)u;
}
__device__ __forceinline__ float bf2f(unsigned int lo16) {
    unsigned int v = lo16 << 16;
    return __builtin_bit_cast(float, v);
}
__device__ __forceinline__ void cvt8(const uint4& v, float* f) {
    f[0] = bf2f(v.x & 0xFFFFu); f[1] = bf2f(v.x >> 16);
    f[2] = bf2f(v.y & 0xFFFFu); f[3] = bf2f(v.y >> 16);
    f[4] = bf2f(v.z & 0xFFFFu); f[5] = bf2f(v.z >> 16);
    f[6] = bf2f(v.w & 0xFFFFu); f[7] = bf2f(v.w >> 16);
}

// --- A1: bucket histogram (bucket = dst >> 9) ---
__global__ __launch_bounds__(256) void bucket_hist_kernel(const int* __restrict__ dst,
                                                          int* __restrict__ bcount, int E) {
    __shared__ int h[256];
    int t = threadIdx.x;
    h[t] = 0;
    __syncthreads();
    int base = blockIdx.x * 4096;
#pragma unroll
    for (int i = 0; i < 16; ++i) {
        int e = base + t + i * 256;
        if (e < E) atomicAdd(&h[dst[e] >> 9], 1);
    }
    __syncthreads();
    if (h[t] > 0) atomicAdd(&bcount[t], h[t]);
}

__global__ void bucket_scan_kernel(const int* __restrict__ bcount, int* __restrict__ bstart,
                                   int* __restrict__ rs8, int NB, int N, int E) {
    __shared__ int s[256];
    int t = threadIdx.x;
    int v = (t < NB) ? bcount[t] : 0;
    s[t] = v;
    __syncthreads();
    for (int off = 1; off < 256; off <<= 1) {
        int tmp = 0;
        if (t >= off) tmp = s[t - off];
        __syncthreads();
        s[t] += tmp;
        __syncthreads();
    }
    bstart[t] = s[t] - v;
    if (t == 255) bstart[256] = s[255];
    if (t == 0) rs8[(size_t)N * 8] = E;   // global end sentinel
}

// --- A2: stage packed (src | local_dst<<17) into bucket windows ---
__global__ __launch_bounds__(256) void bucket_scatter_kernel(const int* __restrict__ src,
                                                             const int* __restrict__ dst,
                                                             const int* __restrict__ bstart,
                                                             int* __restrict__ bfill,
                                                             unsigned int* __restrict__ stage,
                                                             int E) {
    __shared__ int hist[256];
    __shared__ int abase[256];
    int t = threadIdx.x;
    hist[t] = 0;
    __syncthreads();
    int base = blockIdx.x * 4096;
#pragma unroll
    for (int i = 0; i < 16; ++i) {
        int e = base + t + i * 256;
        if (e < E) atomicAdd(&hist[dst[e] >> 9], 1);
    }
    __syncthreads();
    if (hist[t] > 0) {
        int r = atomicAdd(&bfill[t], hist[t]);
        abase[t] = bstart[t] + r;
    }
    __syncthreads();
    hist[t] = 0;
    __syncthreads();
#pragma unroll
    for (int i = 0; i < 16; ++i) {
        int e = base + t + i * 256;
        if (e < E) {
            int d = dst[e];
            int b = d >> 9;
            int slot = atomicAdd(&hist[b], 1);
            stage[abase[b] + slot] = (unsigned)src[e] | ((unsigned)(d & 511) << 17);
        }
    }
}

// --- B: per-bucket CSR finalize with per-(node, src-bucket-of-8) sub-lists ---
__global__ __launch_bounds__(256) void csr_build_kernel(const unsigned int* __restrict__ stage,
                                                        const int* __restrict__ bstart,
                                                        int* __restrict__ rs8,
                                                        float* __restrict__ dis,
                                                        int* __restrict__ csr_src, int N) {
    __shared__ int cnt[4096];   // (node local 512) x (src bucket 8)
    __shared__ int psum[256];
    int b = blockIdx.x, t = threadIdx.x;
    int node0 = b << 9;
#pragma unroll
    for (int q = 0; q < 16; ++q) cnt[t + q * 256] = 0;
    __syncthreads();
    int eb = bstart[b], ee = bstart[b + 1];
    for (int e = eb + t; e < ee; e += 256) {
        unsigned w = stage[e];
        int l = w >> 17;
        int s = (int)(w & 0x1FFFFu);
        int sb = (int)(((unsigned long long)(unsigned)s * 8u) / (unsigned)N);
        atomicAdd(&cnt[l * 8 + sb], 1);
    }
    __syncthreads();
    int loc[16];
    int run = 0;
#pragma unroll
    for (int k = 0; k < 16; ++k) { loc[k] = run; run += cnt[16 * t + k]; }
    psum[t] = run;
    __syncthreads();
    for (int off = 1; off < 256; off <<= 1) {
        int tmp = 0;
        if (t >= off) tmp = psum[t - off];
        __syncthreads();
        psum[t] += tmp;
        __syncthreads();
    }
    int base = psum[t] - run;
    int dega = loc[8];
    int degb = run - loc[8];
    // cnt[16t+k] read/written only by thread t -> no extra sync needed
#pragma unroll
    for (int k = 0; k < 16; ++k) cnt[16 * t + k] = base + loc[k];
    int na = node0 + 2 * t, nb2 = na + 1;
    if (na < N) {
        dis[na] = rsqrtf(1.f + (float)dega);
#pragma unroll
        for (int k = 0; k < 8; ++k) rs8[(size_t)na * 8 + k] = eb + base + loc[k];
    }
    if (nb2 < N) {
        dis[nb2] = rsqrtf(1.f + (float)degb);
#pragma unroll
        for (int k = 0; k < 8; ++k) rs8[(size_t)nb2 * 8 + k] = eb + base + loc[8 + k];
    }
    __syncthreads();
    for (int e = eb + t; e < ee; e += 256) {
        unsigned w = stage[e];
        int l = w >> 17;
        int s = (int)(w & 0x1FFFFu);
        int sb = (int)(((unsigned long long)(unsigned)s * 8u) / (unsigned)N);
        int slot = atomicAdd(&cnt[l * 8 + sb], 1);
        csr_src[eb + slot] = s;
    }
}

// --- register-blocked GEMM: C[M][NC] = X[M][K] @ W[K][NC]. ---
template <int K, int NC, bool IN_BF16, bool OUT_BF16>
__global__ __launch_bounds__(256) void gemm_kernel(const void* __restrict__ Xv,
                                                   const float* __restrict__ W,
                                                   const float* __restrict__ bias,
                                                   void* __restrict__ Cv, int M) {
    constexpr int TM = 128, KT = 32;
    constexpr int CL = NC / 8;
    constexpr int RL = 256 / CL;
    constexpr int RPT = TM / RL;
    constexpr int XSTR = KT + 1;
    constexpr int WSTR = NC + 12;

    __shared__ float XL[TM * XSTR];
    __shared__ float WL[KT * WSTR];

    int tid = threadIdx.x;
    int tx = tid % CL, ty = tid / CL;
    int rowBase = blockIdx.x * TM;
    const int wgo = tx * 8 + ((tx >> 2) << 2);

    float4 acc0[RPT], acc1[RPT];
#pragma unroll
    for (int i = 0; i < RPT; ++i) {
        acc0[i] = make_float4(0.f, 0.f, 0.f, 0.f);
        acc1[i] = make_float4(0.f, 0.f, 0.f, 0.f);
    }

    for (int kk = 0; kk < K; kk += KT) {
        if (IN_BF16) {
            const unsigned short* Xb = (const unsigned short*)Xv;
#pragma unroll
            for (int q = 0; q < 2; ++q) {
                int li = q * 256 + tid;
                int r = li >> 2, c8 = (li & 3) * 8;
                int gr = rowBase + r;
                if (gr >= M) gr = M - 1;
                uint4 v = *(const uint4*)&Xb[(size_t)gr * K + kk + c8];
                float f[8];
                cvt8(v, f);
#pragma unroll
                for (int j = 0; j < 8; ++j) XL[r * XSTR + c8 + j] = f[j];
            }
        } else {
            const float* Xf = (const float*)Xv;
#pragma unroll
            for (int q = 0; q < 4; ++q) {
                int li = q * 256 + tid;
                int r = li >> 3, c4 = (li & 7) * 4;
                int gr = rowBase + r;
                if (gr >= M) gr = M - 1;
                float4 v = *(const float4*)&Xf[(size_t)gr * K + kk + c4];
                XL[r * XSTR + c4 + 0] = v.x;
                XL[r * XSTR + c4 + 1] = v.y;
                XL[r * XSTR + c4 + 2] = v.z;
                XL[r * XSTR + c4 + 3] = v.w;
            }
        }
        constexpr int WCH = KT * NC / 4 / 256;
#pragma unroll
        for (int q = 0; q < WCH; ++q) {
            int li = q * 256 + tid;
            int k = li / (NC / 4), c = (li % (NC / 4)) * 4;
            int g = c >> 3;
            float4 v = *(const float4*)&W[(size_t)(kk + k) * NC + c];
            *(float4*)&WL[k * WSTR + g * 8 + ((g >> 2) << 2) + (c & 7)] = v;
        }
        __syncthreads();
#pragma unroll
        for (int k = 0; k < KT; ++k) {
            float4 w0 = *(const float4*)&WL[k * WSTR + wgo];
            float4 w1 = *(const float4*)&WL[k * WSTR + wgo + 4];
            float xv[RPT];
#pragma unroll
            for (int i = 0; i < RPT; ++i) xv[i] = XL[(ty * RPT + i) * XSTR + k];
#pragma unroll
            for (int i = 0; i < RPT; ++i) {
                acc0[i].x += xv[i] * w0.x; acc0[i].y += xv[i] * w0.y;
                acc0[i].z += xv[i] * w0.z; acc0[i].w += xv[i] * w0.w;
                acc1[i].x += xv[i] * w1.x; acc1[i].y += xv[i] * w1.y;
                acc1[i].z += xv[i] * w1.z; acc1[i].w += xv[i] * w1.w;
            }
        }
        __syncthreads();
    }

    float4 b0 = make_float4(0.f, 0.f, 0.f, 0.f), b1 = b0;
    if (bias) {
        b0 = *(const float4*)&bias[tx * 8];
        b1 = *(const float4*)&bias[tx * 8 + 4];
    }
#pragma unroll
    for (int i = 0; i < RPT; ++i) {
        int gr = rowBase + ty * RPT + i;
        if (gr < M) {
            float4 v0 = acc0[i], v1 = acc1[i];
            v0.x += b0.x; v0.y += b0.y; v0.z += b0.z; v0.w += b0.w;
            v1.x += b1.x; v1.y += b1.y; v1.z += b1.z; v1.w += b1.w;
            if (OUT_BF16) {
                unsigned short* Cb = (unsigned short*)Cv;
                uint4 o;
                o.x = (unsigned)f2bf(v0.x) | ((unsigned)f2bf(v0.y) << 16);
                o.y = (unsigned)f2bf(v0.z) | ((unsigned)f2bf(v0.w) << 16);
                o.z = (unsigned)f2bf(v1.x) | ((unsigned)f2bf(v1.y) << 16);
                o.w = (unsigned)f2bf(v1.z) | ((unsigned)f2bf(v1.w) << 16);
                *(uint4*)&Cb[(size_t)gr * NC + tx * 8] = o;
            } else {
                float* Cf = (float*)Cv;
                *(float4*)&Cf[(size_t)gr * NC + tx * 8] = v0;
                *(float4*)&Cf[(size_t)gr * NC + tx * 8 + 4] = v1;
            }
        }
    }
}

// --- phase-locked multi-pass aggregate: full-wave rows, reg accumulators.
//     Pass p touches only src slice [p*N/8,(p+1)*N/8) -> per-XCD L2 resident.
//     out = relu(d*(sum_e dis[s]*h[s] + d*h[n]) + bias), bf16.
template <int NC>
__global__ __launch_bounds__(256, 4) void aggregate_pass_kernel(
    const unsigned short* __restrict__ h, const float* __restrict__ dis,
    const int* __restrict__ rs8, const int* __restrict__ csr_src,
    const float* __restrict__ bias, unsigned short* __restrict__ out, int N) {
    constexpr int NPW = 25;        // nodes per wave
    constexpr int EPL = NC / 64;   // elements per lane (2 or 1)
    int wid = (blockIdx.x * blockDim.x + threadIdx.x) >> 6;
    int lane = threadIdx.x & 63;
    int nbase = wid * NPW;

    float acc[NPW][EPL];
    // init with self term d*h[n]
#pragma unroll
    for (int i = 0; i < NPW; ++i) {
        int n = nbase + i;
        bool v = (n < N);
        float d = v ? dis[n] : 0.f;
        if (EPL == 2) {
            unsigned hv = v ? ((const unsigned*)h)[(size_t)n * 64 + lane] : 0u;
            acc[i][0] = __builtin_bit_cast(float, hv << 16) * d;
            acc[i][1] = __builtin_bit_cast(float, hv & 0xFFFF0000u) * d;
        } else {
            unsigned short hv = v ? h[(size_t)n * 64 + lane] : (unsigned short)0;
            acc[i][0] = bf2f(hv) * d;
        }
    }

    for (int p = 0; p < 8; ++p) {
#pragma unroll
        for (int i = 0; i < NPW; ++i) {
            int n = nbase + i;
            if (n >= N) break;  // wave-uniform
            int beg = rs8[(size_t)n * 8 + p], end = rs8[(size_t)n * 8 + p + 1];
            for (int e0 = beg; e0 < end; e0 += 64) {
                int idx = e0 + lane;
                int sv = 0;
                float dv = 0.f;
                if (idx < end) { sv = csr_src[idx]; dv = dis[sv]; }
                int cnt = min(64, end - e0);
                for (int j = 0; j < cnt; j += 4) {
                    int ss[4];
                    float cc[4];
#pragma unroll
                    for (int k = 0; k < 4; ++k) {
                        int jj = j + k;
                        ss[k] = __shfl(sv, jj);
                        float c = __shfl(dv, jj);
                        cc[k] = (jj < cnt) ? c : 0.f;
                    }
                    if (EPL == 2) {
                        unsigned vv[4];
#pragma unroll
                        for (int k = 0; k < 4; ++k)
                            vv[k] = ((const unsigned*)h)[(size_t)ss[k] * 64 + lane];
#pragma unroll
                        for (int k = 0; k < 4; ++k) {
                            acc[i][0] += __builtin_bit_cast(float, vv[k] << 16) * cc[k];
                            acc[i][1] += __builtin_bit_cast(float, vv[k] & 0xFFFF0000u) * cc[k];
                        }
                    } else {
                        unsigned short vv[4];
#pragma unroll
                        for (int k = 0; k < 4; ++k) vv[k] = h[(size_t)ss[k] * 64 + lane];
#pragma unroll
                        for (int k = 0; k < 4; ++k)
                            acc[i][0] += bf2f(vv[k]) * cc[k];
                    }
                }
            }
        }
        __syncthreads();   // keep block's waves (and roughly all blocks) in phase
    }

    // epilogue
#pragma unroll
    for (int i = 0; i < NPW; ++i) {
        int n = nbase + i;
        if (n >= N) break;
        float d = dis[n];
        if (EPL == 2) {
            float2 bv = ((const float2*)bias)[lane];
            float r0 = fmaxf(acc[i][0] * d + bv.x, 0.f);
            float r1 = fmaxf(acc[i][1] * d + bv.y, 0.f);
            unsigned o = (unsigned)f2bf(r0) | ((unsigned)f2bf(r1) << 16);
            ((unsigned*)out)[(size_t)n * 64 + lane] = o;
        } else {
            float r = fmaxf(acc[i][0] * d + bias[lane], 0.f);
            out[(size_t)n * 64 + lane] = f2bf(r);
        }
    }
}

// --- pool h2 (bf16, N x 64) -> gsum[64 graphs x 64 feats] (batch sorted) ---
__global__ __launch_bounds__(64) void pool_kernel(const unsigned short* __restrict__ h2,
                                                  const int* __restrict__ batch,
                                                  float* __restrict__ gsum, int N) {
    int f = threadIdx.x;
    int n0 = blockIdx.x * 256;
    int nend = min(n0 + 256, N);
    float acc = 0.f;
    int gcur = batch[n0];
    for (int n = n0; n < nend; ++n) {
        int g = batch[n];
        if (g != gcur) {
            atomicAdd(&gsum[gcur * 64 + f], acc);
            acc = 0.f;
            gcur = g;
        }
        acc += bf2f(h2[(size_t)n * 64 + f]);
    }
    atomicAdd(&gsum[gcur * 64 + f], acc);
}

__global__ __launch_bounds__(256) void count_batch_kernel(const int* __restrict__ batch,
                                                          int* __restrict__ gcnt, int N) {
    __shared__ int lc[64];
    int t = threadIdx.x;
    if (t < 64) lc[t] = 0;
    __syncthreads();
    int n = blockIdx.x * blockDim.x + t;
    if (n < N) atomicAdd(&lc[batch[n]], 1);
    __syncthreads();
    if (t < 64 && lc[t] > 0) atomicAdd(&gcnt[t], lc[t]);
}

// --- head: ge = pooled_h2 @ Wf1 + bf1 ; ic = ge @ Wf2 + bf2 ---
__global__ __launch_bounds__(128) void head_kernel(const float* __restrict__ gsum,
                                                   const int* __restrict__ gcnt,
                                                   const float* __restrict__ Wf1,
                                                   const float* __restrict__ bf1,
                                                   const float* __restrict__ Wf2,
                                                   const float* __restrict__ bf2,
                                                   float* __restrict__ out) {
    __shared__ float ph[64];
    __shared__ float red0[128], red1[128];
    int g = blockIdx.x, f = threadIdx.x;
    if (f < 64) ph[f] = gsum[g * 64 + f] / (float)max(gcnt[g], 1);
    __syncthreads();
    float ge = bf1[f];
#pragma unroll 8
    for (int k = 0; k < 64; ++k) ge += ph[k] * Wf1[k * 128 + f];
    out[g * 128 + f] = ge;
    red0[f] = ge * Wf2[f * 2 + 0];
    red1[f] = ge * Wf2[f * 2 + 1];
    __syncthreads();
    for (int off = 64; off > 0; off >>= 1) {
        if (f < off) { red0[f] += red0[f + off]; red1[f] += red1[f + off]; }
        __syncthreads();
    }
    if (f == 0) {
        out[8192 + 1 + g * 2 + 0] = red0[0] + bf2[0];
        out[8192 + 1 + g * 2 + 1] = red1[0] + bf2[1];
        if (g == 0) out[8192] = 0.f;
    }
}

extern "C" void kernel_launch(void* const* d_in, const int* in_sizes, int n_in,
                              void* d_out, int out_size, void* d_ws, size_t ws_size,
                              hipStream_t stream) {
    const float* x   = (const float*)d_in[0];
    const float* W1  = (const float*)d_in[1];
    const float* b1  = (const float*)d_in[2];
    const float* W2  = (const float*)d_in[3];
    const float* b2  = (const float*)d_in[4];
    const float* Wf1 = (const float*)d_in[5];
    const float* bf1 = (const float*)d_in[6];
    const float* Wf2 = (const float*)d_in[7];
    const float* bf2 = (const float*)d_in[8];
    const int* edge  = (const int*)d_in[9];
    const int* batch = (const int*)d_in[10];

    const int N = in_sizes[10];      // 100000
    const int E = in_sizes[9] / 2;   // 3200000
    const int* srcA = edge;
    const int* dstA = edge + E;
    float* out = (float*)d_out;

    const int NB = (N + 511) >> 9;   // dst buckets of 512 nodes

    char* p = (char*)d_ws;
    auto alloc = [&](size_t bytes) {
        char* r = p;
        p += (bytes + 255) & ~(size_t)255;
        return r;
    };
    float* gsum     = (float*)alloc(64 * 64 * 4);
    int*   gcnt     = (int*)alloc(64 * 4);
    int*   bcount   = (int*)alloc(256 * 4);
    int*   bfill    = (int*)alloc(256 * 4);
    size_t zbytes   = (size_t)(p - (char*)d_ws);
    int*   bstart   = (int*)alloc(260 * 4);
    float* dis      = (float*)alloc((size_t)N * 4);
    int*   rs8      = (int*)alloc(((size_t)N * 8 + 1) * 4);
    unsigned int* stage = (unsigned int*)alloc((size_t)E * 4);
    int*   csr_src  = (int*)alloc((size_t)E * 4);
    float* bufA     = (float*)alloc((size_t)N * 128 * 2);  // bf16 h (128) then g (64)
    float* bufB     = (float*)alloc((size_t)N * 128 * 2);  // bf16 h1 (128) then h2 (64)

    unsigned short* bufAb = (unsigned short*)bufA;
    unsigned short* bufBb = (unsigned short*)bufB;

    hipMemsetAsync(d_ws, 0, zbytes, stream);

    const int EB = (E + 4095) / 4096;
    bucket_hist_kernel<<<EB, 256, 0, stream>>>(dstA, bcount, E);
    bucket_scan_kernel<<<1, 256, 0, stream>>>(bcount, bstart, rs8, NB, N, E);
    bucket_scatter_kernel<<<EB, 256, 0, stream>>>(srcA, dstA, bstart, bfill, stage, E);
    csr_build_kernel<<<NB, 256, 0, stream>>>(stage, bstart, rs8, dis, csr_src, N);

    const int GB = (N + 127) / 128;
    const int AB = (N + 99) / 100;   // 4 waves x 25 nodes per block
    // layer 1
    gemm_kernel<128, 128, false, true><<<GB, 256, 0, stream>>>(x, W1, nullptr, bufAb, N);
    aggregate_pass_kernel<128><<<AB, 256, 0, stream>>>(bufAb, dis, rs8, csr_src, b1,
                                                       bufBb, N);
    // layer 2
    gemm_kernel<128, 64, true, true><<<GB, 256, 0, stream>>>(bufBb, W2, nullptr, bufAb, N);
    aggregate_pass_kernel<64><<<AB, 256, 0, stream>>>(bufAb, dis, rs8, csr_src, b2,
                                                      bufBb, N);
    // head: pool(h2) then tiny GEMMs (linearity: pool(h2@Wf1+bf1)=pool(h2)@Wf1+bf1)
    pool_kernel<<<(N + 255) / 256, 64, 0, stream>>>(bufBb, batch, gsum, N);
    count_batch_kernel<<<(N + 255) / 256, 256, 0, stream>>>(batch, gcnt, N);
    head_kernel<<<64, 128, 0, stream>>>(gsum, gcnt, Wf1, bf1, Wf2, bf2, out);
}

// Round 8
// 483.236 us; speedup vs baseline: 2.0199x; 2.0199x over previous
//
#include <hip/hip_runtime.h>

// ---------------------------------------------------------------------------
// GCN forward, bf16 activations / fp32 accum.
// CSR: bucketed radix (dst>>9, 512 nodes/bucket), contiguous per-node lists.
// GEMM1/2: MFMA v_mfma_f32_32x32x16_bf16, LDS-free: A-frags streamed from
//   row-major bf16 (16B/lane), W pre-packed to fragment order (held in VGPRs).
// Aggregate: R5 sub-wave uint4 gather (known-good 108us form).
// Head: pool(h2) first (linearity), then tiny 64-graph GEMMs.
// ---------------------------------------------------------------------------

typedef __attribute__((ext_vector_type(8))) short bfrag;     // 8 bf16 = 4 VGPR
typedef __attribute__((ext_vector_type(16))) float f32x16;   // MFMA C/D

__device__ __forceinline__ unsigned short f2bf(float f) {
    unsigned int u = __builtin_bit_cast(unsigned int, f);
    u = (u + 0x7FFFu + ((u >> 16) & 1u)) >> 16;
    return (unsigned short)u;
}
__device__ __forceinline__ float bf2f(unsigned int lo16) {
    unsigned int v = lo16 << 16;
    return __builtin_bit_cast(float, v);
}

// --- A1: bucket histogram (bucket = dst >> 9) ---
__global__ __launch_bounds__(256) void bucket_hist_kernel(const int* __restrict__ dst,
                                                          int* __restrict__ bcount, int E) {
    __shared__ int h[256];
    int t = threadIdx.x;
    h[t] = 0;
    __syncthreads();
    int base = blockIdx.x * 4096;
#pragma unroll
    for (int i = 0; i < 16; ++i) {
        int e = base + t + i * 256;
        if (e < E) atomicAdd(&h[dst[e] >> 9], 1);
    }
    __syncthreads();
    if (h[t] > 0) atomicAdd(&bcount[t], h[t]);
}

__global__ void bucket_scan_kernel(const int* __restrict__ bcount, int* __restrict__ bstart,
                                   int* __restrict__ rowstart, int NB, int N, int E) {
    __shared__ int s[256];
    int t = threadIdx.x;
    int v = (t < NB) ? bcount[t] : 0;
    s[t] = v;
    __syncthreads();
    for (int off = 1; off < 256; off <<= 1) {
        int tmp = 0;
        if (t >= off) tmp = s[t - off];
        __syncthreads();
        s[t] += tmp;
        __syncthreads();
    }
    bstart[t] = s[t] - v;
    if (t == 255) bstart[256] = s[255];
    if (t == 0) rowstart[N] = E;
}

// --- A2: stage packed (src | local_dst<<17) into bucket windows ---
__global__ __launch_bounds__(256) void bucket_scatter_kernel(const int* __restrict__ src,
                                                             const int* __restrict__ dst,
                                                             const int* __restrict__ bstart,
                                                             int* __restrict__ bfill,
                                                             unsigned int* __restrict__ stage,
                                                             int E) {
    __shared__ int hist[256];
    __shared__ int abase[256];
    int t = threadIdx.x;
    hist[t] = 0;
    __syncthreads();
    int base = blockIdx.x * 4096;
#pragma unroll
    for (int i = 0; i < 16; ++i) {
        int e = base + t + i * 256;
        if (e < E) atomicAdd(&hist[dst[e] >> 9], 1);
    }
    __syncthreads();
    if (hist[t] > 0) {
        int r = atomicAdd(&bfill[t], hist[t]);
        abase[t] = bstart[t] + r;
    }
    __syncthreads();
    hist[t] = 0;
    __syncthreads();
#pragma unroll
    for (int i = 0; i < 16; ++i) {
        int e = base + t + i * 256;
        if (e < E) {
            int d = dst[e];
            int b = d >> 9;
            int slot = atomicAdd(&hist[b], 1);
            stage[abase[b] + slot] = (unsigned)src[e] | ((unsigned)(d & 511) << 17);
        }
    }
}

// --- B: per-bucket CSR finalize (R5 version) ---
__global__ __launch_bounds__(256) void csr_build_kernel(const unsigned int* __restrict__ stage,
                                                        const int* __restrict__ bstart,
                                                        int* __restrict__ rowstart,
                                                        float* __restrict__ dis,
                                                        int* __restrict__ csr_src, int N) {
    __shared__ int cnt[512];
    __shared__ int ofs[512];
    __shared__ int psum[256];
    int b = blockIdx.x, t = threadIdx.x;
    int node0 = b << 9;
    int nb = min(512, N - node0);
    cnt[t] = 0;
    cnt[t + 256] = 0;
    __syncthreads();
    int eb = bstart[b], ee = bstart[b + 1];
    for (int e = eb + t; e < ee; e += 256) {
        unsigned w = stage[e];
        atomicAdd(&cnt[w >> 17], 1);
    }
    __syncthreads();
    int a = cnt[2 * t], c = cnt[2 * t + 1];
    int ps = a + c;
    psum[t] = ps;
    __syncthreads();
    for (int off = 1; off < 256; off <<= 1) {
        int tmp = 0;
        if (t >= off) tmp = psum[t - off];
        __syncthreads();
        psum[t] += tmp;
        __syncthreads();
    }
    int ex = psum[t] - ps;
    ofs[2 * t] = ex;
    ofs[2 * t + 1] = ex + a;
    if (2 * t < nb) {
        rowstart[node0 + 2 * t] = eb + ex;
        dis[node0 + 2 * t] = rsqrtf(1.f + (float)a);
    }
    if (2 * t + 1 < nb) {
        rowstart[node0 + 2 * t + 1] = eb + ex + a;
        dis[node0 + 2 * t + 1] = rsqrtf(1.f + (float)c);
    }
    __syncthreads();
    for (int e = eb + t; e < ee; e += 256) {
        unsigned w = stage[e];
        int l = w >> 17;
        int slot = atomicAdd(&ofs[l], 1);
        csr_src[eb + slot] = (int)(w & 0x1FFFFu);
    }
}

// --- x fp32 -> bf16 row-major ---
__global__ __launch_bounds__(256) void xprep_kernel(const float* __restrict__ x,
                                                    unsigned short* __restrict__ xb,
                                                    int total8) {
    int idx = blockIdx.x * blockDim.x + threadIdx.x;
    if (idx >= total8) return;
    const float4* xf = (const float4*)x;
    float4 v0 = xf[idx * 2 + 0];
    float4 v1 = xf[idx * 2 + 1];
    uint4 o;
    o.x = (unsigned)f2bf(v0.x) | ((unsigned)f2bf(v0.y) << 16);
    o.y = (unsigned)f2bf(v0.z) | ((unsigned)f2bf(v0.w) << 16);
    o.z = (unsigned)f2bf(v1.x) | ((unsigned)f2bf(v1.y) << 16);
    o.w = (unsigned)f2bf(v1.z) | ((unsigned)f2bf(v1.w) << 16);
    *(uint4*)&xb[idx * 8] = o;
}

// --- pack W[K][NC] fp32 -> bf16 MFMA B-frag order ---
//     frag (kt,ct), lane l: elems j=0..7 -> W[kt*16 + 8*(l>>5)+j][ct*32 + (l&31)]
template <int K, int NC>
__global__ __launch_bounds__(256) void wprep_kernel(const float* __restrict__ W,
                                                    unsigned short* __restrict__ Wf) {
    constexpr int CT = NC / 32, KT = K / 16;
    int idx = blockIdx.x * blockDim.x + threadIdx.x;
    if (idx >= KT * CT * 64) return;
    int l = idx & 63;
    int fi = idx >> 6;
    int ct = fi % CT, kt = fi / CT;
    int n = ct * 32 + (l & 31);
    int k0 = kt * 16 + 8 * (l >> 5);
    unsigned short v[8];
#pragma unroll
    for (int j = 0; j < 8; ++j) v[j] = f2bf(W[(size_t)(k0 + j) * NC + n]);
    uint4 o;
    o.x = (unsigned)v[0] | ((unsigned)v[1] << 16);
    o.y = (unsigned)v[2] | ((unsigned)v[3] << 16);
    o.z = (unsigned)v[4] | ((unsigned)v[5] << 16);
    o.w = (unsigned)v[6] | ((unsigned)v[7] << 16);
    *(uint4*)&Wf[(size_t)idx * 8] = o;
}

// --- MFMA GEMM: C[M][NC](bf16) = A[M][K](bf16) @ Wf(frag-packed bf16) ---
//     One wave per 32-row tile. W frags live in VGPRs; A streamed from global.
template <int K, int NC>
__global__ __launch_bounds__(256) void gemm_mfma_kernel(const unsigned short* __restrict__ A,
                                                        const unsigned short* __restrict__ Wf,
                                                        unsigned short* __restrict__ C,
                                                        int M) {
    constexpr int KT = K / 16, CT = NC / 32;
    int wid = (blockIdx.x * blockDim.x + threadIdx.x) >> 6;
    int lane = threadIdx.x & 63;
    int row0 = wid * 32;
    if (row0 >= M) return;

    bfrag B[KT][CT];
#pragma unroll
    for (int kt = 0; kt < KT; ++kt)
#pragma unroll
        for (int ct = 0; ct < CT; ++ct)
            B[kt][ct] = *(const bfrag*)&Wf[(size_t)((kt * CT + ct) * 64 + lane) * 8];

    f32x16 acc[CT];
#pragma unroll
    for (int ct = 0; ct < CT; ++ct)
#pragma unroll
        for (int i = 0; i < 16; ++i) acc[ct][i] = 0.f;

    int r = row0 + (lane & 31);
    if (r >= M) r = M - 1;
    const unsigned short* Arow = &A[(size_t)r * K + 8 * (lane >> 5)];
#pragma unroll
    for (int kt = 0; kt < KT; ++kt) {
        bfrag a = *(const bfrag*)&Arow[kt * 16];
#pragma unroll
        for (int ct = 0; ct < CT; ++ct)
            acc[ct] = __builtin_amdgcn_mfma_f32_32x32x16_bf16(a, B[kt][ct], acc[ct], 0, 0, 0);
    }

    // C/D layout: col = lane&31, row = (reg&3) + 8*(reg>>2) + 4*(lane>>5)
    int colb = lane & 31;
    int rowq = 4 * (lane >> 5);
#pragma unroll
    for (int ct = 0; ct < CT; ++ct) {
        int col = ct * 32 + colb;
#pragma unroll
        for (int rg = 0; rg < 16; ++rg) {
            int row = row0 + (rg & 3) + 8 * (rg >> 2) + rowq;
            if (row < M) C[(size_t)row * NC + col] = f2bf(acc[ct][rg]);
        }
    }
}

// --- wave-per-node bf16 gather aggregation (R5 form, fp32 accum) ---
template <int NC>
__global__ __launch_bounds__(256) void aggregate_kernel(const unsigned short* __restrict__ h,
                                                        const float* __restrict__ dis,
                                                        const int* __restrict__ rowstart,
                                                        const int* __restrict__ csr_src,
                                                        const float* __restrict__ bias,
                                                        unsigned short* __restrict__ out,
                                                        int N) {
    constexpr int LPR = NC / 8;   // lanes per row (16B = 8 bf16 each)
    constexpr int RPS = 64 / LPR; // rows (edges) per step
    int wid = (blockIdx.x * blockDim.x + threadIdx.x) >> 6;
    int lane = threadIdx.x & 63;
    if (wid >= N) return;
    int n = wid;
    int sub = lane / LPR;
    int fid = lane % LPR;
    const uint4* h4 = (const uint4*)h;
    float d = dis[n];
    float acc[8];
#pragma unroll
    for (int i = 0; i < 8; ++i) acc[i] = 0.f;
    if (sub == 0) {
        uint4 hv = h4[(size_t)n * LPR + fid];
        acc[0] = bf2f(hv.x & 0xFFFFu) * d; acc[1] = bf2f(hv.x >> 16) * d;
        acc[2] = bf2f(hv.y & 0xFFFFu) * d; acc[3] = bf2f(hv.y >> 16) * d;
        acc[4] = bf2f(hv.z & 0xFFFFu) * d; acc[5] = bf2f(hv.z >> 16) * d;
        acc[6] = bf2f(hv.w & 0xFFFFu) * d; acc[7] = bf2f(hv.w >> 16) * d;
    }

    int beg = rowstart[n], end = rowstart[n + 1];
    for (int e0 = beg; e0 < end; e0 += 64) {
        int idx = e0 + lane;
        int sv = 0;
        float dv = 0.f;
        if (idx < end) { sv = csr_src[idx]; dv = dis[sv]; }
        int cnt = min(64, end - e0);
        int j = 0;
        for (; j + 2 * RPS <= cnt; j += 2 * RPS) {
            int ja = j + sub, jb = j + RPS + sub;
            int sa = __shfl(sv, ja); float ca = __shfl(dv, ja);
            int sb = __shfl(sv, jb); float cb = __shfl(dv, jb);
            uint4 va = h4[(size_t)sa * LPR + fid];
            uint4 vb = h4[(size_t)sb * LPR + fid];
            acc[0] += bf2f(va.x & 0xFFFFu) * ca + bf2f(vb.x & 0xFFFFu) * cb;
            acc[1] += bf2f(va.x >> 16) * ca + bf2f(vb.x >> 16) * cb;
            acc[2] += bf2f(va.y & 0xFFFFu) * ca + bf2f(vb.y & 0xFFFFu) * cb;
            acc[3] += bf2f(va.y >> 16) * ca + bf2f(vb.y >> 16) * cb;
            acc[4] += bf2f(va.z & 0xFFFFu) * ca + bf2f(vb.z & 0xFFFFu) * cb;
            acc[5] += bf2f(va.z >> 16) * ca + bf2f(vb.z >> 16) * cb;
            acc[6] += bf2f(va.w & 0xFFFFu) * ca + bf2f(vb.w & 0xFFFFu) * cb;
            acc[7] += bf2f(va.w >> 16) * ca + bf2f(vb.w >> 16) * cb;
        }
        for (; j < cnt; j += RPS) {
            int jj = j + sub;
            int jc = min(jj, cnt - 1);
            int s = __shfl(sv, jc);
            float c = __shfl(dv, jc);
            if (jj >= cnt) c = 0.f;
            uint4 v = h4[(size_t)s * LPR + fid];
            acc[0] += bf2f(v.x & 0xFFFFu) * c; acc[1] += bf2f(v.x >> 16) * c;
            acc[2] += bf2f(v.y & 0xFFFFu) * c; acc[3] += bf2f(v.y >> 16) * c;
            acc[4] += bf2f(v.z & 0xFFFFu) * c; acc[5] += bf2f(v.z >> 16) * c;
            acc[6] += bf2f(v.w & 0xFFFFu) * c; acc[7] += bf2f(v.w >> 16) * c;
        }
    }
#pragma unroll
    for (int m = LPR; m < 64; m <<= 1) {
#pragma unroll
        for (int i = 0; i < 8; ++i) acc[i] += __shfl_xor(acc[i], m);
    }
    if (sub == 0) {
        const float4 bv0 = *(const float4*)&bias[fid * 8 + 0];
        const float4 bv1 = *(const float4*)&bias[fid * 8 + 4];
        float r[8];
        r[0] = fmaxf(acc[0] * d + bv0.x, 0.f);
        r[1] = fmaxf(acc[1] * d + bv0.y, 0.f);
        r[2] = fmaxf(acc[2] * d + bv0.z, 0.f);
        r[3] = fmaxf(acc[3] * d + bv0.w, 0.f);
        r[4] = fmaxf(acc[4] * d + bv1.x, 0.f);
        r[5] = fmaxf(acc[5] * d + bv1.y, 0.f);
        r[6] = fmaxf(acc[6] * d + bv1.z, 0.f);
        r[7] = fmaxf(acc[7] * d + bv1.w, 0.f);
        uint4 o;
        o.x = (unsigned)f2bf(r[0]) | ((unsigned)f2bf(r[1]) << 16);
        o.y = (unsigned)f2bf(r[2]) | ((unsigned)f2bf(r[3]) << 16);
        o.z = (unsigned)f2bf(r[4]) | ((unsigned)f2bf(r[5]) << 16);
        o.w = (unsigned)f2bf(r[6]) | ((unsigned)f2bf(r[7]) << 16);
        *(uint4*)&out[(size_t)n * NC + fid * 8] = o;
    }
}

// --- pool h2 (bf16, N x 64) -> gsum[64 x 64] (batch sorted) ---
__global__ __launch_bounds__(64) void pool_kernel(const unsigned short* __restrict__ h2,
                                                  const int* __restrict__ batch,
                                                  float* __restrict__ gsum, int N) {
    int f = threadIdx.x;
    int n0 = blockIdx.x * 128;
    int nend = min(n0 + 128, N);
    float acc = 0.f;
    int gcur = batch[n0];
    for (int n = n0; n < nend; ++n) {
        int g = batch[n];
        if (g != gcur) {
            atomicAdd(&gsum[gcur * 64 + f], acc);
            acc = 0.f;
            gcur = g;
        }
        acc += bf2f(h2[(size_t)n * 64 + f]);
    }
    atomicAdd(&gsum[gcur * 64 + f], acc);
}

__global__ __launch_bounds__(256) void count_batch_kernel(const int* __restrict__ batch,
                                                          int* __restrict__ gcnt, int N) {
    __shared__ int lc[64];
    int t = threadIdx.x;
    if (t < 64) lc[t] = 0;
    __syncthreads();
    int n = blockIdx.x * blockDim.x + t;
    if (n < N) atomicAdd(&lc[batch[n]], 1);
    __syncthreads();
    if (t < 64 && lc[t] > 0) atomicAdd(&gcnt[t], lc[t]);
}

// --- head: ge = pooled_h2 @ Wf1 + bf1 ; ic = ge @ Wf2 + bf2 ---
__global__ __launch_bounds__(128) void head_kernel(const float* __restrict__ gsum,
                                                   const int* __restrict__ gcnt,
                                                   const float* __restrict__ Wf1,
                                                   const float* __restrict__ bf1,
                                                   const float* __restrict__ Wf2,
                                                   const float* __restrict__ bf2,
                                                   float* __restrict__ out) {
    __shared__ float ph[64];
    __shared__ float red0[128], red1[128];
    int g = blockIdx.x, f = threadIdx.x;
    if (f < 64) ph[f] = gsum[g * 64 + f] / (float)max(gcnt[g], 1);
    __syncthreads();
    float ge = bf1[f];
#pragma unroll 8
    for (int k = 0; k < 64; ++k) ge += ph[k] * Wf1[k * 128 + f];
    out[g * 128 + f] = ge;
    red0[f] = ge * Wf2[f * 2 + 0];
    red1[f] = ge * Wf2[f * 2 + 1];
    __syncthreads();
    for (int off = 64; off > 0; off >>= 1) {
        if (f < off) { red0[f] += red0[f + off]; red1[f] += red1[f + off]; }
        __syncthreads();
    }
    if (f == 0) {
        out[8192 + 1 + g * 2 + 0] = red0[0] + bf2[0];
        out[8192 + 1 + g * 2 + 1] = red1[0] + bf2[1];
        if (g == 0) out[8192] = 0.f;
    }
}

extern "C" void kernel_launch(void* const* d_in, const int* in_sizes, int n_in,
                              void* d_out, int out_size, void* d_ws, size_t ws_size,
                              hipStream_t stream) {
    const float* x   = (const float*)d_in[0];
    const float* W1  = (const float*)d_in[1];
    const float* b1  = (const float*)d_in[2];
    const float* W2  = (const float*)d_in[3];
    const float* b2  = (const float*)d_in[4];
    const float* Wf1 = (const float*)d_in[5];
    const float* bf1 = (const float*)d_in[6];
    const float* Wf2 = (const float*)d_in[7];
    const float* bf2 = (const float*)d_in[8];
    const int* edge  = (const int*)d_in[9];
    const int* batch = (const int*)d_in[10];

    const int N = in_sizes[10];      // 100000
    const int E = in_sizes[9] / 2;   // 3200000
    const int* srcA = edge;
    const int* dstA = edge + E;
    float* out = (float*)d_out;

    const int NB = (N + 511) >> 9;   // dst buckets of 512 nodes

    char* p = (char*)d_ws;
    auto alloc = [&](size_t bytes) {
        char* r = p;
        p += (bytes + 255) & ~(size_t)255;
        return r;
    };
    float* gsum     = (float*)alloc(64 * 64 * 4);
    int*   gcnt     = (int*)alloc(64 * 4);
    int*   bcount   = (int*)alloc(256 * 4);
    int*   bfill    = (int*)alloc(256 * 4);
    size_t zbytes   = (size_t)(p - (char*)d_ws);
    int*   bstart   = (int*)alloc(260 * 4);
    float* dis      = (float*)alloc((size_t)N * 4);
    int*   rowstart = (int*)alloc((size_t)(N + 1) * 4);
    unsigned short* Wp1 = (unsigned short*)alloc(8 * 4 * 64 * 8 * 2);  // 32 KB
    unsigned short* Wp2 = (unsigned short*)alloc(8 * 2 * 64 * 8 * 2);  // 16 KB
    unsigned int* stage = (unsigned int*)alloc((size_t)E * 4);
    int*   csr_src  = (int*)alloc((size_t)E * 4);
    unsigned short* xb = (unsigned short*)alloc((size_t)N * 128 * 2);
    unsigned short* bufAb = (unsigned short*)alloc((size_t)N * 128 * 2);
    unsigned short* bufBb = (unsigned short*)alloc((size_t)N * 128 * 2);

    hipMemsetAsync(d_ws, 0, zbytes, stream);

    const int EB = (E + 4095) / 4096;
    bucket_hist_kernel<<<EB, 256, 0, stream>>>(dstA, bcount, E);
    bucket_scan_kernel<<<1, 256, 0, stream>>>(bcount, bstart, rowstart, NB, N, E);
    bucket_scatter_kernel<<<EB, 256, 0, stream>>>(srcA, dstA, bstart, bfill, stage, E);
    csr_build_kernel<<<NB, 256, 0, stream>>>(stage, bstart, rowstart, dis, csr_src, N);

    // weight + input prep for MFMA GEMMs
    xprep_kernel<<<(N * 128 / 8 + 255) / 256, 256, 0, stream>>>(x, xb, N * 128 / 8);
    wprep_kernel<128, 128><<<8, 256, 0, stream>>>(W1, Wp1);
    wprep_kernel<128, 64><<<4, 256, 0, stream>>>(W2, Wp2);

    const int TILES = (N + 31) / 32;
    const int GB = (TILES + 3) / 4;
    // layer 1: h = x@W1 (bf16) ; h1 = relu(d*(sum dis_s*h_s + d*h_n) + b1)
    gemm_mfma_kernel<128, 128><<<GB, 256, 0, stream>>>(xb, Wp1, bufAb, N);
    aggregate_kernel<128><<<(N + 3) / 4, 256, 0, stream>>>(bufAb, dis, rowstart, csr_src,
                                                           b1, bufBb, N);
    // layer 2: g = h1@W2 ; h2 = relu(...)
    gemm_mfma_kernel<128, 64><<<GB, 256, 0, stream>>>(bufBb, Wp2, bufAb, N);
    aggregate_kernel<64><<<(N + 3) / 4, 256, 0, stream>>>(bufAb, dis, rowstart, csr_src,
                                                          b2, bufBb, N);
    // head: pool(h2) then tiny GEMMs (pool(h2@Wf1+bf1) = pool(h2)@Wf1+bf1)
    pool_kernel<<<(N + 127) / 128, 64, 0, stream>>>(bufBb, batch, gsum, N);
    count_batch_kernel<<<(N + 255) / 256, 256, 0, stream>>>(batch, gcnt, N);
    head_kernel<<<64, 128, 0, stream>>>(gsum, gcnt, Wf1, bf1, Wf2, bf2, out);
}